// Round 10
// baseline (1010.837 us; speedup 1.0000x reference)
//
#include <hip/hip_runtime.h>

// LSTM (B=2048, T=1024, I=8, H=64) + sigmoid(FC), bf16 MFMA.
// Round 10: R=2 rows/block -> 1024 blocks = 4 blocks/CU (4 independent
// barrier groups per SIMD cover chain latency). x-projection done per-thread
// in registers (v_dot2_f32_bf16, fp32-FMA fallback) -> no x-MFMA, no xg LDS:
// in-loop MFMA 12 -> 8 per wave, chain depth 2.
// Gate-strided M-tiles (wave wv owns tiles {4g+wv}): acc[g] = gate-type g of
// jh = 16wv+4g4+rsel, col nib; col carries row nib&1 (8 copies). Thread
// activates one element (cndmask tree over acc regs) + adds its in-register
// xg. One barrier/step; h double-buffered, stride 96 shorts -> the 8 fh
// b128 lines land on 8 disjoint bank quads (conflict-free).

namespace {
constexpr int T_LEN = 1024;
constexpr int R     = 2;     // batch rows per block
constexpr int TSX   = 64;    // timesteps per x chunk
constexpr int HPS   = 96;    // h row stride (shorts) = 48 dw

typedef __attribute__((ext_vector_type(8))) short  short8v;
typedef __attribute__((ext_vector_type(4))) float  float4v;
typedef unsigned short u16;
typedef unsigned int   u32;
typedef unsigned long long u64;

#if defined(__has_builtin)
#if __has_builtin(__builtin_amdgcn_fdot2_f32_bf16)
#define HAVE_DOT2BF 1
typedef __attribute__((ext_vector_type(2))) __bf16 bf16x2;
#endif
#endif

__device__ __forceinline__ float fsig(float x) {
  return __builtin_amdgcn_rcpf(1.f + __expf(-x));
}
__device__ __forceinline__ float ftanh(float x) {
  return 1.f - 2.f * __builtin_amdgcn_rcpf(__expf(2.f * x) + 1.f);
}
__device__ __forceinline__ u16 f2bf(float f) {  // RNE
  u32 u = __float_as_uint(f);
  u32 r = ((u >> 16) & 1u) + 0x7fffu;
  return (u16)((u + r) >> 16);
}

__global__ __launch_bounds__(256, 4) void lstm_r2(
    const float* __restrict__ x,     // [B, T, 8]
    const float* __restrict__ W_ih,  // [256, 8]
    const float* __restrict__ W_hh,  // [256, 64]
    const float* __restrict__ b_ih,  // [256]
    const float* __restrict__ b_hh,  // [256]
    const float* __restrict__ fc_w,  // [64]
    const float* __restrict__ fc_b,  // [1]
    float* __restrict__ out) {       // [B]
  __shared__ __align__(16) u16   x_lds[2][TSX][R][8];  // 4 KB bf16 x
  __shared__ __align__(16) u16   h_lds[2][R][HPS];     // 768 B
  __shared__ __align__(16) float hf[R][64];            // final h (fp32)

  const int tid  = threadIdx.x;
  const int lane = tid & 63;
  const int wv   = tid >> 6;        // wave 0..3
  const int g4   = lane >> 4;       // MFMA k-quad / C row-quad
  const int nib  = lane & 15;       // MFMA m/n coord
  const int row  = nib & 1;         // batch row (cols duplicate x8)
  const int cp   = nib >> 1;        // copy index 0..7
  const int rsel = cp & 3;          // which acc reg this thread activates
  const int jh   = 16 * wv + 4 * g4 + rsel;   // owned h index
  const bool actown = (cp < 4);     // one of the 2 dup threads writes h
  const int bBase = blockIdx.x * R;

  // ---- static A fragments (h-GEMM only): wave wv owns tiles q=4g+wv ----
  // ah0[g] = W_hh[:,0:32], ah1[g] = W_hh[:,32:64]; A[m=16q+nib][k=8*g4+j].
  short8v ah0[4], ah1[4];
  for (int g = 0; g < 4; ++g) {
    const int n = 16 * (4 * g + wv) + nib;  // gate row
    short8v f0, f1;
    for (int j = 0; j < 8; ++j) {
      const int k = 8 * g4 + j;
      f0[j] = (short)f2bf(W_hh[n * 64 + k]);
      f1[j] = (short)f2bf(W_hh[n * 64 + 32 + k]);
    }
    ah0[g] = f0; ah1[g] = f1;
  }

  // ---- per-thread x-projection weights: rows 64g+jh of W_ih + fused bias ----
  float bsum[4];
#ifdef HAVE_DOT2BF
  u32 wpk[4][4];  // bf16x2-packed, low short = even channel
#else
  float wf[4][8];
#endif
  for (int g = 0; g < 4; ++g) {
    const int ng = 64 * g + jh;
    bsum[g] = b_ih[ng] + b_hh[ng];
#ifdef HAVE_DOT2BF
    for (int p = 0; p < 4; ++p)
      wpk[g][p] = (u32)f2bf(W_ih[ng * 8 + 2 * p]) |
                  ((u32)f2bf(W_ih[ng * 8 + 2 * p + 1]) << 16);
#else
    for (int k = 0; k < 8; ++k) wf[g][k] = W_ih[ng * 8 + k];
#endif
  }

  for (int i = tid; i < 2 * R * HPS; i += 256) ((u16*)h_lds)[i] = 0;  // h0=0

  // ---- x staging: 1 float4/thread per 64-step chunk, double-buffered ----
  const int sr = tid >> 7, sm = tid & 127;       // row, float4-in-row
  const int stt = sm >> 1, sc4 = (sm & 1) * 4;   // dest tt, channel
  float4v xr;
  auto stage_load = [&](int chunk) {
    xr = *(const float4v*)&x[(size_t)(bBase + sr) * (T_LEN * 8) +
                             (size_t)chunk * (TSX * 8) + sm * 4];
  };
  auto stage_write = [&](int buf) {
    union { u64 u; u16 s[4]; } pk;
    pk.s[0] = f2bf(xr[0]); pk.s[1] = f2bf(xr[1]);
    pk.s[2] = f2bf(xr[2]); pk.s[3] = f2bf(xr[3]);
    *(u64*)&x_lds[buf][stt][sr][sc4] = pk.u;
  };

  stage_load(0);
  stage_write(0);
  __syncthreads();

  const bool sel1 = (rsel & 1) != 0;
  const bool sel2 = (rsel & 2) != 0;
  const float4v z4 = {0.f, 0.f, 0.f, 0.f};
  float c = 0.f;

  for (int t = 0; t < T_LEN; ++t) {
    const int hb = t & 1;
    const int buf = (t >> 6) & 1;
    const int tt = t & (TSX - 1);
    if (tt == 0 && t + TSX < T_LEN) stage_load((t >> 6) + 1);

    // ---- chain: h read -> 2-deep MFMA ----
    const short8v fh0 = *(const short8v*)&h_lds[hb][row][8 * g4];
    const short8v fh1 = *(const short8v*)&h_lds[hb][row][32 + 8 * g4];
    float4v acc[4];
#pragma unroll
    for (int g = 0; g < 4; ++g)
      acc[g] = __builtin_amdgcn_mfma_f32_16x16x32_bf16(ah0[g], fh0, z4, 0, 0, 0);
#pragma unroll
    for (int g = 0; g < 4; ++g)
      acc[g] = __builtin_amdgcn_mfma_f32_16x16x32_bf16(ah1[g], fh1, acc[g], 0, 0, 0);

    // ---- off-chain: per-thread xg = W_ih[64g+jh] . x_t[row] + bias ----
    float xg[4];
    {
      union { short8v v; u32 d[4]; float4v f; } xv;
      xv.v = *(const short8v*)&x_lds[buf][tt][row][0];
#ifdef HAVE_DOT2BF
#pragma unroll
      for (int g = 0; g < 4; ++g) {
        float s = bsum[g];
#pragma unroll
        for (int p = 0; p < 4; ++p) {
          union { u32 u; bf16x2 b; } ua, ub;
          ua.u = wpk[g][p]; ub.u = xv.d[p];
          s = __builtin_amdgcn_fdot2_f32_bf16(ua.b, ub.b, s, false);
        }
        xg[g] = s;
      }
#else
      float xf[8];
#pragma unroll
      for (int p = 0; p < 4; ++p) {
        xf[2 * p]     = __uint_as_float(xv.d[p] << 16);
        xf[2 * p + 1] = __uint_as_float(xv.d[p] & 0xffff0000u);
      }
#pragma unroll
      for (int g = 0; g < 4; ++g) {
        float s = bsum[g];
#pragma unroll
        for (int k = 0; k < 8; ++k) s += wf[g][k] * xf[k];
        xg[g] = s;
      }
#endif
    }

    // ---- select owned element, add xg, activate (in-register) ----
    float gv[4];
#pragma unroll
    for (int g = 0; g < 4; ++g) {
      const float x01 = sel1 ? acc[g][1] : acc[g][0];
      const float x23 = sel1 ? acc[g][3] : acc[g][2];
      gv[g] = (sel2 ? x23 : x01) + xg[g];
    }
    const float iv = fsig(gv[0]);
    const float fv = fsig(gv[1]);
    const float gg = ftanh(gv[2]);
    const float ov = fsig(gv[3]);
    c = fv * c + iv * gg;
    const float h = ov * ftanh(c);
    if (actown) {
      h_lds[hb ^ 1][row][jh] = f2bf(h);
      if (t == T_LEN - 1) hf[row][jh] = h;
    }
    if (tt == TSX - 1 && t + 1 < T_LEN) stage_write(buf ^ 1);
    __syncthreads();  // the one barrier per step
  }

  // ---- epilogue: out[b] = sigmoid(hT . fc_w + fc_b) ----
  if (tid < R) {
    float a = fc_b[0];
#pragma unroll
    for (int k = 0; k < 64; ++k) a += hf[tid][k] * fc_w[k];
    out[bBase + tid] = fsig(a);
  }
}
}  // namespace

extern "C" void kernel_launch(void* const* d_in, const int* in_sizes, int n_in,
                              void* d_out, int out_size, void* d_ws,
                              size_t ws_size, hipStream_t stream) {
  const float* x    = (const float*)d_in[0];
  const float* W_ih = (const float*)d_in[1];
  const float* W_hh = (const float*)d_in[2];
  const float* b_ih = (const float*)d_in[3];
  const float* b_hh = (const float*)d_in[4];
  const float* fc_w = (const float*)d_in[5];
  const float* fc_b = (const float*)d_in[6];
  float* out = (float*)d_out;

  const int B = in_sizes[0] / (T_LEN * 8);  // 2048
  lstm_r2<<<dim3(B / R), dim3(256), 0, stream>>>(x, W_ih, W_hh, b_ih, b_hh,
                                                 fc_w, fc_b, out);
}